// Round 11
// baseline (506.508 us; speedup 1.0000x reference)
//
#include <hip/hip_runtime.h>
#include <float.h>

#define D_DIM 768
#define K_DIM 500
#define NDT   24          // 768 / 32 D-tiles
#define BM    64          // rows per block
#define NTH   256
#define PB_STRIDE 100352  // padded per-half partial stride (rows)

typedef _Float16 f16x8  __attribute__((ext_vector_type(8)));
typedef float    f32x16 __attribute__((ext_vector_type(16)));

// ws layout:
//   0        : cnorm   float[512]                 (2 KB)
//   4096     : partial double[16*512]             (64 KB)
//   131072   : BpH     _Float16[24*512*32]        (768 KB)
//   917504   : BpL     _Float16[24*512*32]        (768 KB)
//   1703936  : pbv     float[2*PB_STRIDE]         (~800 KB)
//   2506752  : pbi     int[2*PB_STRIDE]           (~800 KB)

// ---------------- cnorm prep (exact, fp64) ----------------
__global__ void cnorm_partial_kernel(const float* __restrict__ C,
                                     double* __restrict__ partial, int K) {
    const int k = threadIdx.x;
    const int w = blockIdx.x;    // 0..15
    double s = 0.0;
    if (k < K) {
        const int d0 = w * (D_DIM / 16);
        for (int d = d0; d < d0 + (D_DIM / 16); ++d) {
            const float c = C[(size_t)d * K + k];
            s = fma((double)c, (double)c, s);
        }
    }
    partial[w * 512 + k] = s;
}

__global__ void cnorm_finish_kernel(const double* __restrict__ partial,
                                    float* __restrict__ cnorm, int K) {
    const int k = threadIdx.x;
    if (k < K) {
        double s = 0.0;
        for (int w = 0; w < 16; ++w) s += partial[w * 512 + k];
        cnorm[k] = (float)s;
    } else {
        cnorm[k] = FLT_MAX;
    }
}

// ---------------- pack C into fragment-ready f16 hi/lo planes ----------------
// Bp[dt][col][k0..31]. For the 32x32x16 path, chunk (step*2 + kh) holds
// k = step*16 + kh*8 .. +8 — same bytes, different consumer indexing.
__global__ void packB_kernel(const float* __restrict__ C,
                             _Float16* __restrict__ BpH,
                             _Float16* __restrict__ BpL) {
    const int idx = blockIdx.x * 256 + threadIdx.x;   // 0..12287
    const int col = idx & 511;
    const int dt  = idx >> 9;                         // 0..23
    f16x8 h[4], l[4];
    #pragma unroll
    for (int c = 0; c < 4; ++c)
        #pragma unroll
        for (int j = 0; j < 8; ++j) {
            const int k = c * 8 + j;
            const float v = (col < K_DIM)
                          ? C[(size_t)(dt * 32 + k) * K_DIM + col] : 0.0f;
            const _Float16 hh = (_Float16)v;
            h[c][j] = hh;
            l[c][j] = (_Float16)(v - (float)hh);
        }
    f16x8* dH = (f16x8*)(BpH + ((size_t)dt * 512 + col) * 32);
    f16x8* dL = (f16x8*)(BpL + ((size_t)dt * 512 + col) * 32);
    #pragma unroll
    for (int c = 0; c < 4; ++c) { dH[c] = h[c]; dL[c] = l[c]; }
}

// ---- main: barrier-free, LDS-free fp16-split 32x32x16 MFMA, partial argmin --
__launch_bounds__(NTH, 3)
__global__ void assign_kernel(const float* __restrict__ feat,
                              const _Float16* __restrict__ BpH,
                              const _Float16* __restrict__ BpL,
                              const float* __restrict__ cnorm,
                              float* __restrict__ pbv,
                              int* __restrict__ pbi,
                              int T) {
    __shared__ float red_v[BM * 4];   // epilogue scratch only
    __shared__ int   red_i[BM * 4];

    const int tid  = threadIdx.x;
    const int wn   = tid >> 6;    // 0..3 (64-col slice)
    const int lane = tid & 63;
    const int c5   = lane & 31;   // row/col within 32-frag
    const int kh   = lane >> 5;   // k-half 0..1
    const int bid  = blockIdx.x;
    const int half = bid & 1;     // col half
    const int R0   = (bid >> 1) * BM;

    // A row base pointers for m = 0,1 (row clamp; dup rows discarded at write).
    // kh*8 floats folded in: per dt, chunk kh floats at +dt*32, chunk 2+kh at +dt*32+16.
    int r0 = R0 + c5;      r0 = r0 < T ? r0 : T - 1;
    int r1 = R0 + 32 + c5; r1 = r1 < T ? r1 : T - 1;
    const float* apA = feat + (size_t)r0 * D_DIM + kh * 8;
    const float* apB = feat + (size_t)r1 * D_DIM + kh * 8;

    // B fragment base: global col = half*256 + wn*64 + n*32 + c5, chunk kh
    const int colbase = half * 256 + wn * 64 + c5;
    const _Float16* bph = BpH + (size_t)colbase * 32 + kh * 8;
    const _Float16* bpl = BpL + (size_t)colbase * 32 + kh * 8;

    f32x16 acc[2][2];
    #pragma unroll
    for (int m = 0; m < 2; ++m)
        #pragma unroll
        for (int n = 0; n < 2; ++n)
            #pragma unroll
            for (int r = 0; r < 16; ++r) acc[m][n][r] = 0.0f;

#define SPLIT8(V0, V1, H, L) do {                                              \
    const float fa_[8] = {(V0).x, (V0).y, (V0).z, (V0).w,                      \
                          (V1).x, (V1).y, (V1).z, (V1).w};                     \
    _Pragma("unroll")                                                          \
    for (int j = 0; j < 8; ++j) {                                              \
        const _Float16 hh = (_Float16)fa_[j];                                  \
        (H)[j] = hh; (L)[j] = (_Float16)(fa_[j] - (float)hh);                  \
    }                                                                          \
} while (0)

    #pragma unroll 1
    for (int dt = 0; dt < NDT; ++dt) {
        // ---- raw A loads (issued first: the convert's vmcnt wait retires A
        //      while the later-issued B loads stay in flight)
        const float* pa = apA + dt * 32;
        const float* pb = apB + dt * 32;
        const float4 ra0 = *(const float4*)(pa);
        const float4 ra1 = *(const float4*)(pa + 4);
        const float4 ra2 = *(const float4*)(pa + 16);
        const float4 ra3 = *(const float4*)(pa + 20);
        const float4 rb0 = *(const float4*)(pb);
        const float4 rb1 = *(const float4*)(pb + 4);
        const float4 rb2 = *(const float4*)(pb + 16);
        const float4 rb3 = *(const float4*)(pb + 20);

        // ---- B step-0 fragments (n = 0,1)
        const size_t bo = (size_t)dt * 16384;   // dt*512*32 elements
        const f16x8 b0H0 = *(const f16x8*)(bph + bo);
        const f16x8 b0H1 = *(const f16x8*)(bph + bo + 1024);
        const f16x8 b0L0 = *(const f16x8*)(bpl + bo);
        const f16x8 b0L1 = *(const f16x8*)(bpl + bo + 1024);

        // ---- in-register fp32 -> f16 hi/lo split (covers B latency)
        f16x8 aH[2][2], aL[2][2];
        SPLIT8(ra0, ra1, aH[0][0], aL[0][0]);
        SPLIT8(ra2, ra3, aH[0][1], aL[0][1]);
        SPLIT8(rb0, rb1, aH[1][0], aL[1][0]);
        SPLIT8(rb2, rb3, aH[1][1], aL[1][1]);

        // ---- B step-1 fragments (issued before step-0 MFMAs; retire under them)
        const f16x8 b1H0 = *(const f16x8*)(bph + bo + 16);
        const f16x8 b1H1 = *(const f16x8*)(bph + bo + 1024 + 16);
        const f16x8 b1L0 = *(const f16x8*)(bpl + bo + 16);
        const f16x8 b1L1 = *(const f16x8*)(bpl + bo + 1024 + 16);

        // ---- MFMA step 0 (12 x 32x32x16)
        __builtin_amdgcn_s_setprio(1);
        acc[0][0] = __builtin_amdgcn_mfma_f32_32x32x16_f16(aH[0][0], b0H0, acc[0][0], 0, 0, 0);
        acc[0][0] = __builtin_amdgcn_mfma_f32_32x32x16_f16(aL[0][0], b0H0, acc[0][0], 0, 0, 0);
        acc[0][0] = __builtin_amdgcn_mfma_f32_32x32x16_f16(aH[0][0], b0L0, acc[0][0], 0, 0, 0);
        acc[1][0] = __builtin_amdgcn_mfma_f32_32x32x16_f16(aH[1][0], b0H0, acc[1][0], 0, 0, 0);
        acc[1][0] = __builtin_amdgcn_mfma_f32_32x32x16_f16(aL[1][0], b0H0, acc[1][0], 0, 0, 0);
        acc[1][0] = __builtin_amdgcn_mfma_f32_32x32x16_f16(aH[1][0], b0L0, acc[1][0], 0, 0, 0);
        acc[0][1] = __builtin_amdgcn_mfma_f32_32x32x16_f16(aH[0][0], b0H1, acc[0][1], 0, 0, 0);
        acc[0][1] = __builtin_amdgcn_mfma_f32_32x32x16_f16(aL[0][0], b0H1, acc[0][1], 0, 0, 0);
        acc[0][1] = __builtin_amdgcn_mfma_f32_32x32x16_f16(aH[0][0], b0L1, acc[0][1], 0, 0, 0);
        acc[1][1] = __builtin_amdgcn_mfma_f32_32x32x16_f16(aH[1][0], b0H1, acc[1][1], 0, 0, 0);
        acc[1][1] = __builtin_amdgcn_mfma_f32_32x32x16_f16(aL[1][0], b0H1, acc[1][1], 0, 0, 0);
        acc[1][1] = __builtin_amdgcn_mfma_f32_32x32x16_f16(aH[1][0], b0L1, acc[1][1], 0, 0, 0);

        // ---- MFMA step 1
        acc[0][0] = __builtin_amdgcn_mfma_f32_32x32x16_f16(aH[0][1], b1H0, acc[0][0], 0, 0, 0);
        acc[0][0] = __builtin_amdgcn_mfma_f32_32x32x16_f16(aL[0][1], b1H0, acc[0][0], 0, 0, 0);
        acc[0][0] = __builtin_amdgcn_mfma_f32_32x32x16_f16(aH[0][1], b1L0, acc[0][0], 0, 0, 0);
        acc[1][0] = __builtin_amdgcn_mfma_f32_32x32x16_f16(aH[1][1], b1H0, acc[1][0], 0, 0, 0);
        acc[1][0] = __builtin_amdgcn_mfma_f32_32x32x16_f16(aL[1][1], b1H0, acc[1][0], 0, 0, 0);
        acc[1][0] = __builtin_amdgcn_mfma_f32_32x32x16_f16(aH[1][1], b1L0, acc[1][0], 0, 0, 0);
        acc[0][1] = __builtin_amdgcn_mfma_f32_32x32x16_f16(aH[0][1], b1H1, acc[0][1], 0, 0, 0);
        acc[0][1] = __builtin_amdgcn_mfma_f32_32x32x16_f16(aL[0][1], b1H1, acc[0][1], 0, 0, 0);
        acc[0][1] = __builtin_amdgcn_mfma_f32_32x32x16_f16(aH[0][1], b1L1, acc[0][1], 0, 0, 0);
        acc[1][1] = __builtin_amdgcn_mfma_f32_32x32x16_f16(aH[1][1], b1H1, acc[1][1], 0, 0, 0);
        acc[1][1] = __builtin_amdgcn_mfma_f32_32x32x16_f16(aL[1][1], b1H1, acc[1][1], 0, 0, 0);
        acc[1][1] = __builtin_amdgcn_mfma_f32_32x32x16_f16(aH[1][1], b1L1, acc[1][1], 0, 0, 0);
        __builtin_amdgcn_s_setprio(0);
    }
#undef SPLIT8

    // ---------------- epilogue: partial argmin over this block's 256 cols ----
    // C/D layout (m74/m101): col = lane&31, row = (r&3) + 8*(r>>2) + 4*(lane>>5)
    float cn[2];
    #pragma unroll
    for (int n = 0; n < 2; ++n)
        cn[n] = cnorm[half * 256 + wn * 64 + n * 32 + c5];

    #pragma unroll
    for (int m = 0; m < 2; ++m) {
        #pragma unroll
        for (int r = 0; r < 16; ++r) {
            float best = cn[0] - 2.0f * acc[m][0][r];
            int   bi   = colbase;                       // n = 0 col
            {
                const float s = cn[1] - 2.0f * acc[m][1][r];
                if (s < best) { best = s; bi = colbase + 32; }  // tie keeps n=0
            }
            #pragma unroll
            for (int msk = 1; msk < 32; msk <<= 1) {    // stays within 32-lane half
                const float ov = __shfl_xor(best, msk, 64);
                const int   oi = __shfl_xor(bi,   msk, 64);
                if (ov < best || (ov == best && oi < bi)) { best = ov; bi = oi; }
            }
            if (c5 == 0) {
                const int rl = m * 32 + 4 * kh + (r & 3) + 8 * (r >> 2);
                red_v[rl * 4 + wn] = best;
                red_i[rl * 4 + wn] = bi;
            }
        }
    }
    __syncthreads();

    if (tid < BM) {
        float bv = red_v[tid * 4];
        int   bi = red_i[tid * 4];
        #pragma unroll
        for (int w = 1; w < 4; ++w) {
            const float v = red_v[tid * 4 + w];
            const int   i = red_i[tid * 4 + w];
            if (v < bv || (v == bv && i < bi)) { bv = v; bi = i; }
        }
        const int r = R0 + tid;
        if (r < T) {
            pbv[(size_t)half * PB_STRIDE + r] = bv;
            pbi[(size_t)half * PB_STRIDE + r] = bi;
        }
    }
}

// ---------------- combine the two col-half partials ----------------
__global__ void combine_kernel(const float* __restrict__ pbv,
                               const int* __restrict__ pbi,
                               int* __restrict__ out, int T) {
    const int r = blockIdx.x * 256 + threadIdx.x;
    if (r < T) {
        const float s0 = pbv[r];
        const int   i0 = pbi[r];
        const float s1 = pbv[PB_STRIDE + r];
        const int   i1 = pbi[PB_STRIDE + r];
        // exact tie -> half 0 (lower index), matching numpy argmin
        out[r] = (s1 < s0) ? i1 : i0;
    }
}

extern "C" void kernel_launch(void* const* d_in, const int* in_sizes, int n_in,
                              void* d_out, int out_size, void* d_ws, size_t ws_size,
                              hipStream_t stream) {
    const float* feat = (const float*)d_in[0];
    const float* C    = (const float*)d_in[1];
    int* out          = (int*)d_out;
    const int T = in_sizes[0] / D_DIM;   // 100000
    const int K = in_sizes[1] / D_DIM;   // 500

    float*     cnorm   = (float*)d_ws;
    double*    partial = (double*)((char*)d_ws + 4096);
    _Float16*  BpH     = (_Float16*)((char*)d_ws + 131072);
    _Float16*  BpL     = (_Float16*)((char*)d_ws + 917504);
    float*     pbv     = (float*)((char*)d_ws + 1703936);
    int*       pbi     = (int*)((char*)d_ws + 2506752);

    hipLaunchKernelGGL(cnorm_partial_kernel, dim3(16), dim3(512), 0, stream,
                       C, partial, K);
    hipLaunchKernelGGL(cnorm_finish_kernel, dim3(1), dim3(512), 0, stream,
                       partial, cnorm, K);
    hipLaunchKernelGGL(packB_kernel, dim3(48), dim3(256), 0, stream,
                       C, BpH, BpL);

    const int nrb = (T + BM - 1) / BM;            // row blocks
    hipLaunchKernelGGL(assign_kernel, dim3(nrb * 2), dim3(NTH), 0, stream,
                       feat, BpH, BpL, cnorm, pbv, pbi, T);
    hipLaunchKernelGGL(combine_kernel, dim3((T + 255) / 256), dim3(256), 0, stream,
                       pbv, pbi, out, T);
}

// Round 12
// 297.508 us; speedup vs baseline: 1.7025x; 1.7025x over previous
//
#include <hip/hip_runtime.h>
#include <float.h>

#define D_DIM 768
#define K_DIM 500
#define NDT   24          // 768 / 32 D-tiles
#define BM    64          // rows per block
#define NTH   512         // 8 waves: wn = 0..7, each 64 rows x 32 cols
#define PB_STRIDE 100352  // padded per-half partial stride (rows)

typedef _Float16 f16x8 __attribute__((ext_vector_type(8)));
typedef _Float16 f16x4 __attribute__((ext_vector_type(4)));
typedef float    f32x4 __attribute__((ext_vector_type(4)));

// ws layout:
//   0        : cnorm   float[512]                 (2 KB)
//   4096     : partial double[16*512]             (64 KB)
//   131072   : BpH     _Float16[24*512*32]        (768 KB)
//   917504   : BpL     _Float16[24*512*32]        (768 KB)
//   1703936  : pbv     float[2*PB_STRIDE]         (~800 KB)
//   2506752  : pbi     int[2*PB_STRIDE]           (~800 KB)

// ---------------- cnorm prep (exact, fp64) ----------------
__global__ void cnorm_partial_kernel(const float* __restrict__ C,
                                     double* __restrict__ partial, int K) {
    const int k = threadIdx.x;
    const int w = blockIdx.x;    // 0..15
    double s = 0.0;
    if (k < K) {
        const int d0 = w * (D_DIM / 16);
        for (int d = d0; d < d0 + (D_DIM / 16); ++d) {
            const float c = C[(size_t)d * K + k];
            s = fma((double)c, (double)c, s);
        }
    }
    partial[w * 512 + k] = s;
}

__global__ void cnorm_finish_kernel(const double* __restrict__ partial,
                                    float* __restrict__ cnorm, int K) {
    const int k = threadIdx.x;
    if (k < K) {
        double s = 0.0;
        for (int w = 0; w < 16; ++w) s += partial[w * 512 + k];
        cnorm[k] = (float)s;
    } else {
        cnorm[k] = FLT_MAX;
    }
}

// ---------------- pack C into fragment-ready f16 hi/lo planes ----------------
__global__ void packB_kernel(const float* __restrict__ C,
                             _Float16* __restrict__ BpH,
                             _Float16* __restrict__ BpL) {
    const int idx = blockIdx.x * 256 + threadIdx.x;   // 0..12287
    const int col = idx & 511;
    const int dt  = idx >> 9;                         // 0..23
    f16x8 h[4], l[4];
    #pragma unroll
    for (int c = 0; c < 4; ++c)
        #pragma unroll
        for (int j = 0; j < 8; ++j) {
            const int k = c * 8 + j;
            const float v = (col < K_DIM)
                          ? C[(size_t)(dt * 32 + k) * K_DIM + col] : 0.0f;
            const _Float16 hh = (_Float16)v;
            h[c][j] = hh;
            l[c][j] = (_Float16)(v - (float)hh);
        }
    f16x8* dH = (f16x8*)(BpH + ((size_t)dt * 512 + col) * 32);
    f16x8* dL = (f16x8*)(BpL + ((size_t)dt * 512 + col) * 32);
    #pragma unroll
    for (int c = 0; c < 4; ++c) { dH[c] = h[c]; dL[c] = l[c]; }
}

// --- main: 8-wave col-split fp16-split MFMA, B reg-dbuf, 4 waves/SIMD --------
__launch_bounds__(NTH, 4)
__global__ void assign_kernel(const float* __restrict__ feat,
                              const _Float16* __restrict__ BpH,
                              const _Float16* __restrict__ BpL,
                              const float* __restrict__ cnorm,
                              float* __restrict__ pbv,
                              int* __restrict__ pbi,
                              int T) {
    // A tiles double-buffered: 2 planes x 2 bufs x 4KB = 16KB (+4KB reduce)
    __shared__ __align__(16) _Float16 AsH[2][BM * 32];
    __shared__ __align__(16) _Float16 AsL[2][BM * 32];
    __shared__ float red_v[BM * 8];
    __shared__ int   red_i[BM * 8];

    const int tid  = threadIdx.x;
    const int wn   = tid >> 6;    // 0..7 (32-col slice)
    const int lane = tid & 63;
    const int l15  = lane & 15;
    const int kg   = lane >> 4;   // 0..3 (k-group)
    const int bid  = blockIdx.x;
    const int half = bid & 1;     // col half: 0 -> cols 0..255, 1 -> 256..511
    const int R0   = (bid >> 1) * BM;

    // A staging map: 8 threads per row, 4 floats each
    const int ar = tid >> 3;            // 0..63
    const int jj = tid & 7;             // 0..7
    const bool arow_ok = (R0 + ar) < T;
    const float* fptr = feat + (size_t)(R0 + ar) * D_DIM + jj * 4;
    // chunk = jj>>1 (8-float group), hb = jj&1 (which half of the chunk)
    const int aslot = (((jj >> 1) + (ar >> 1)) & 3);
    const int aoff  = ar * 32 + aslot * 8 + (jj & 1) * 4;   // f16 element offset

    // B fragment base: global col = half*256 + wn*32 + nh*16 + l15, chunk kg
    const int colbase = half * 256 + wn * 32 + l15;
    const _Float16* bpH = BpH + (size_t)colbase * 32 + kg * 8;
    const _Float16* bpL = BpL + (size_t)colbase * 32 + kg * 8;

    f32x4 acc[4][2];
    #pragma unroll
    for (int m = 0; m < 4; ++m)
        #pragma unroll
        for (int n = 0; n < 2; ++n) acc[m][n] = (f32x4){0.f, 0.f, 0.f, 0.f};

#define CVT_STORE(V, BUF) do {                                                 \
    const float fa_[4] = {(V).x, (V).y, (V).z, (V).w};                         \
    f16x4 h_, l_;                                                              \
    _Pragma("unroll")                                                          \
    for (int j = 0; j < 4; ++j) {                                              \
        const _Float16 hh = (_Float16)fa_[j];                                  \
        h_[j] = hh; l_[j] = (_Float16)(fa_[j] - (float)hh);                    \
    }                                                                          \
    *(f16x4*)(AsH[BUF] + aoff) = h_;                                           \
    *(f16x4*)(AsL[BUF] + aoff) = l_;                                           \
} while (0)

// lgkmcnt-only barrier: LDS producer->consumer ordering without draining the
// in-flight B/A register prefetch (a full __syncthreads would kill it).
#define SOFT_BARRIER() do {                                                    \
    asm volatile("s_waitcnt lgkmcnt(0)" ::: "memory");                         \
    __builtin_amdgcn_s_barrier();                                              \
} while (0)

// One dt. BCH/BCL: B frags for THIS dt (loaded last iter). BNH/BNL receive B
// for dt+1. ACUR: raw A for dt+1 (consumed by CVT here). ANXT: receives dt+2.
#define BODY(DT, BCH, BCL, BNH, BNL, ACUR, ANXT) do {                          \
    const int cur = (DT) & 1;                                                  \
    /* issue next-dt B loads (retire under next iter's counted waits) */       \
    if ((DT) + 1 < NDT) {                                                      \
        const size_t bo1 = (size_t)((DT) + 1) * 16384;                         \
        BNH[0] = *(const f16x8*)(bpH + bo1);                                   \
        BNH[1] = *(const f16x8*)(bpH + bo1 + 512);                             \
        BNL[0] = *(const f16x8*)(bpL + bo1);                                   \
        BNL[1] = *(const f16x8*)(bpL + bo1 + 512);                             \
    }                                                                          \
    /* issue raw A for dt+2 */                                                 \
    if ((DT) + 2 < NDT && arow_ok) {                                           \
        ANXT = *(const float4*)(fptr + ((DT) + 2) * 32);                       \
    }                                                                          \
    /* A fragments from LDS buf[cur] */                                        \
    f16x8 aH[4], aL[4];                                                        \
    _Pragma("unroll")                                                          \
    for (int m = 0; m < 4; ++m) {                                              \
        const int row = m * 16 + l15;                                          \
        const int sl  = (kg + (row >> 1)) & 3;                                 \
        aH[m] = ((const f16x8*)AsH[cur])[row * 4 + sl];                        \
        aL[m] = ((const f16x8*)AsL[cur])[row * 4 + sl];                        \
    }                                                                          \
    /* MFMA: B was prefetched a full iteration ago -> no B-latency wait */     \
    __builtin_amdgcn_s_setprio(1);                                             \
    _Pragma("unroll")                                                          \
    for (int nh = 0; nh < 2; ++nh)                                             \
        _Pragma("unroll")                                                      \
        for (int m = 0; m < 4; ++m) {                                          \
            f32x4 a = acc[m][nh];                                              \
            a = __builtin_amdgcn_mfma_f32_16x16x32_f16(aH[m], BCH[nh], a, 0, 0, 0); \
            a = __builtin_amdgcn_mfma_f32_16x16x32_f16(aL[m], BCH[nh], a, 0, 0, 0); \
            a = __builtin_amdgcn_mfma_f32_16x16x32_f16(aH[m], BCL[nh], a, 0, 0, 0); \
            acc[m][nh] = a;                                                    \
        }                                                                      \
    __builtin_amdgcn_s_setprio(0);                                             \
    /* stage dt+1 tile from ACUR (loaded a full iteration ago) */              \
    if ((DT) + 1 < NDT) {                                                      \
        CVT_STORE(ACUR, cur ^ 1);                                              \
    }                                                                          \
    SOFT_BARRIER();                                                            \
} while (0)

    // ---- prologue: stage dt=0; prefetch B(0) and raw A for dt=1
    {
        float4 v = make_float4(0.f, 0.f, 0.f, 0.f);
        if (arow_ok) v = *(const float4*)(fptr);
        CVT_STORE(v, 0);
    }
    f16x8 bAH[2], bAL[2], bBH[2], bBL[2];
    bAH[0] = *(const f16x8*)(bpH);
    bAH[1] = *(const f16x8*)(bpH + 512);
    bAL[0] = *(const f16x8*)(bpL);
    bAL[1] = *(const f16x8*)(bpL + 512);
    float4 avA = make_float4(0.f, 0.f, 0.f, 0.f), avB = avA;
    if (arow_ok) avA = *(const float4*)(fptr + 32);
    SOFT_BARRIER();

    // ---- main loop, unrolled by 2 for static prefetch register names
    for (int it2 = 0; it2 < NDT; it2 += 2) {
        BODY(it2,     bAH, bAL, bBH, bBL, avA, avB);
        BODY(it2 + 1, bBH, bBL, bAH, bAL, avB, avA);
    }
#undef BODY
#undef SOFT_BARRIER
#undef CVT_STORE

    // ---------------- epilogue: partial argmin over this block's 256 cols ----
    float cn[2];
    #pragma unroll
    for (int nh = 0; nh < 2; ++nh)
        cn[nh] = cnorm[half * 256 + wn * 32 + nh * 16 + l15];

    #pragma unroll
    for (int m = 0; m < 4; ++m) {
        #pragma unroll
        for (int r = 0; r < 4; ++r) {
            float best = cn[0] - 2.0f * acc[m][0][r];
            int   bi   = colbase;
            {
                const int col = colbase + 16;
                const float s = cn[1] - 2.0f * acc[m][1][r];
                if (s < best || (s == best && col < bi)) { best = s; bi = col; }
            }
            #pragma unroll
            for (int msk = 1; msk < 16; msk <<= 1) {
                const float ov = __shfl_xor(best, msk, 64);
                const int   oi = __shfl_xor(bi,   msk, 64);
                if (ov < best || (ov == best && oi < bi)) { best = ov; bi = oi; }
            }
            if (l15 == 0) {
                const int rl = m * 16 + kg * 4 + r;
                red_v[rl * 8 + wn] = best;
                red_i[rl * 8 + wn] = bi;
            }
        }
    }
    __syncthreads();

    if (tid < BM) {
        float bv = red_v[tid * 8];
        int   bi = red_i[tid * 8];
        #pragma unroll
        for (int w = 1; w < 8; ++w) {
            const float v = red_v[tid * 8 + w];
            const int   i = red_i[tid * 8 + w];
            if (v < bv || (v == bv && i < bi)) { bv = v; bi = i; }
        }
        const int r = R0 + tid;
        if (r < T) {
            pbv[(size_t)half * PB_STRIDE + r] = bv;
            pbi[(size_t)half * PB_STRIDE + r] = bi;
        }
    }
}

// ---------------- combine the two col-half partials ----------------
__global__ void combine_kernel(const float* __restrict__ pbv,
                               const int* __restrict__ pbi,
                               int* __restrict__ out, int T) {
    const int r = blockIdx.x * 256 + threadIdx.x;
    if (r < T) {
        const float s0 = pbv[r];
        const int   i0 = pbi[r];
        const float s1 = pbv[PB_STRIDE + r];
        const int   i1 = pbi[PB_STRIDE + r];
        // exact tie -> half 0 (lower index), matching numpy argmin
        out[r] = (s1 < s0) ? i1 : i0;
    }
}

extern "C" void kernel_launch(void* const* d_in, const int* in_sizes, int n_in,
                              void* d_out, int out_size, void* d_ws, size_t ws_size,
                              hipStream_t stream) {
    const float* feat = (const float*)d_in[0];
    const float* C    = (const float*)d_in[1];
    int* out          = (int*)d_out;
    const int T = in_sizes[0] / D_DIM;   // 100000
    const int K = in_sizes[1] / D_DIM;   // 500

    float*     cnorm   = (float*)d_ws;
    double*    partial = (double*)((char*)d_ws + 4096);
    _Float16*  BpH     = (_Float16*)((char*)d_ws + 131072);
    _Float16*  BpL     = (_Float16*)((char*)d_ws + 917504);
    float*     pbv     = (float*)((char*)d_ws + 1703936);
    int*       pbi     = (int*)((char*)d_ws + 2506752);

    hipLaunchKernelGGL(cnorm_partial_kernel, dim3(16), dim3(512), 0, stream,
                       C, partial, K);
    hipLaunchKernelGGL(cnorm_finish_kernel, dim3(1), dim3(512), 0, stream,
                       partial, cnorm, K);
    hipLaunchKernelGGL(packB_kernel, dim3(48), dim3(256), 0, stream,
                       C, BpH, BpL);

    const int nrb = (T + BM - 1) / BM;            // row blocks
    hipLaunchKernelGGL(assign_kernel, dim3(nrb * 2), dim3(NTH), 0, stream,
                       feat, BpH, BpL, cnorm, pbv, pbi, T);
    hipLaunchKernelGGL(combine_kernel, dim3((T + 255) / 256), dim3(256), 0, stream,
                       pbv, pbi, out, T);
}